// Round 8
// baseline (835.223 us; speedup 1.0000x reference)
//
#include <hip/hip_runtime.h>

#define NB 128
#define NT 2048
#define NL 128
#define START_LBL 126
#define STOP_LBL 127

typedef float f2 __attribute__((ext_vector_type(2)));

__device__ __forceinline__ float bcast_lane(float v, int l) {
    // wave-uniform broadcast via readlane -> SGPR (folds as scalar operand)
    return __int_as_float(__builtin_amdgcn_readlane(__float_as_int(v), l));
}

// Pin values as asm-defined: compiler cannot rematerialize them from memory,
// must keep them in VGPRs (round-7 found VGPR_Count=52 -> t2 was being
// re-loaded from L1/L2 every step = the ~400cyc hidden stall).
#define PIN4(a, b, c, d) asm volatile("" : "+v"(a), "+v"(b), "+v"(c), "+v"(d))

// One block per batch, 4 waves (256 thr), 1 wave/SIMD. Wave w owns k in
// [32w, 32w+32); lane holds packed transition pairs (T[k,j0], T[k,j1]) for
// j0=lane, j1=lane+64 -> 64 VGPRs (PINNED), added via v_pk_add_f32.
// Per step: 32 readlane broadcasts of v -> 32 pk_add + 32 max3 -> LDS partials
// part[buf][wave][j] (transposed: conflict-free b32 reads) -> ONE barrier ->
// each wave reads 4 partials for the 32 j's it owns next step.
__global__ __launch_bounds__(256, 1) void crf_viterbi(
    const float* __restrict__ em, const float* __restrict__ tr,
    float* __restrict__ out)
{
    const int b    = blockIdx.x;
    const int tid  = threadIdx.x;
    const int w    = tid >> 6;          // wave 0..3
    const int lane = tid & 63;
    const int j0   = lane;
    const int j1   = lane + 64;
    const int kbase = w << 5;           // this wave's k-range base (32 k's)
    const int l31  = lane & 31;
    const int jj   = kbase + l31;       // the j this lane finalizes (2-way dup)

    __shared__ __align__(16) float part[2][4][NL];    // [buf][wave][j] transposed
    __shared__ __align__(16) float elds[2][32][NL];   // emission chunks
    __shared__ float vfin[NL];

    // ---- packed transition pairs (coalesced: lane-consecutive j)
    f2 t2[32];
#pragma unroll
    for (int kk = 0; kk < 32; ++kk) {
        t2[kk].x = tr[(kbase + kk) * NL + j0];
        t2[kk].y = tr[(kbase + kk) * NL + j1];
    }
    // force register residency (defeat rematerialization/reload)
    PIN4(t2[0],  t2[1],  t2[2],  t2[3]);
    PIN4(t2[4],  t2[5],  t2[6],  t2[7]);
    PIN4(t2[8],  t2[9],  t2[10], t2[11]);
    PIN4(t2[12], t2[13], t2[14], t2[15]);
    PIN4(t2[16], t2[17], t2[18], t2[19]);
    PIN4(t2[20], t2[21], t2[22], t2[23]);
    PIN4(t2[24], t2[25], t2[26], t2[27]);
    PIN4(t2[28], t2[29], t2[30], t2[31]);

    const float* eb = em + (size_t)b * NT * NL;

    // ---- preload emission chunk 0 (16 KB = 4 x 4KB wave-linear loads)
#pragma unroll
    for (int i = 0; i < 4; ++i) {
        const float* src = eb + i * 1024 + tid * 4;
        float* dst = &elds[0][0][0] + i * 1024 + tid * 4;
        __builtin_amdgcn_global_load_lds(
            (const __attribute__((address_space(1))) void*)src,
            (__attribute__((address_space(3))) void*)dst, 16, 0, 0);
    }
    __syncthreads();   // drains vmcnt(0): chunk 0 resident for all waves

    // ---- v0: -10000 except START label = 0 (emissions[:,0] NOT added)
    float vv = (jj == START_LBL) ? 0.0f : -10000.0f;

#pragma unroll 2
    for (int t = 1; t < NT; ++t) {
        const int pb = t & 1;

        // ---- emission read issued EARLY (latency hides under inner issue)
        float e = elds[(t >> 5) & 1][t & 31][jj];

        // issue next emission chunk (31 steps of flight before the drain)
        if ((t & 31) == 1 && t < NT - 32) {
            const int tcn = (t >> 5) + 1;
            const float* srcb = eb + (size_t)tcn * 32 * NL;
            float* dstb = &elds[tcn & 1][0][0];
#pragma unroll
            for (int i = 0; i < 4; ++i) {
                __builtin_amdgcn_global_load_lds(
                    (const __attribute__((address_space(1))) void*)(srcb + i * 1024 + tid * 4),
                    (__attribute__((address_space(3))) void*)(dstb + i * 1024 + tid * 4),
                    16, 0, 0);
            }
        }

        // ---- inner: max over this wave's 32 k's, both j columns packed.
        // 2 alternating accumulator chains per column halve serial max3 depth.
        float a0A = -3.0e38f, a0B = -3.0e38f;
        float a1A = -3.0e38f, a1B = -3.0e38f;
#pragma unroll
        for (int half = 0; half < 2; ++half) {
            // batch 16 broadcasts (independent; live in SGPRs)
            float s[16];
#pragma unroll
            for (int kk = 0; kk < 16; ++kk)
                s[kk] = bcast_lane(vv, half * 16 + kk);
#pragma unroll
            for (int kk = 0; kk < 16; kk += 2) {
                f2 sv0; sv0.x = s[kk];     sv0.y = s[kk];
                f2 sv1; sv1.x = s[kk + 1]; sv1.y = s[kk + 1];
                f2 r0 = t2[half * 16 + kk]     + sv0;   // v_pk_add_f32
                f2 r1 = t2[half * 16 + kk + 1] + sv1;   // v_pk_add_f32
                if ((kk & 2) == 0) {
                    a0A = fmaxf(fmaxf(a0A, r0.x), r1.x);  // v_max3_f32
                    a1A = fmaxf(fmaxf(a1A, r0.y), r1.y);
                } else {
                    a0B = fmaxf(fmaxf(a0B, r0.x), r1.x);
                    a1B = fmaxf(fmaxf(a1B, r0.y), r1.y);
                }
            }
        }
        float a0 = fmaxf(a0A, a0B);
        float a1 = fmaxf(a1A, a1B);

        // transposed partials: write word w*128+j -> bank j&31, 2-way (free)
        part[pb][w][j0] = a0;
        part[pb][w][j1] = a1;

        // ---- ONE barrier/step. Raw s_barrier keeps chunk loads in flight;
        // full __syncthreads (vmcnt drain) only right before a chunk switch.
        if ((t & 31) == 31) {
            __syncthreads();
        } else {
            asm volatile("s_waitcnt lgkmcnt(0)\n\ts_barrier" ::: "memory");
        }

        // ---- finalize: 4 conflict-free b32 reads (bank jj&31, upper half-wave
        // broadcasts), reduce, add emission
        float p0 = part[pb][0][jj];
        float p1 = part[pb][1][jj];
        float p2 = part[pb][2][jj];
        float p3 = part[pb][3][jj];
        float m = fmaxf(fmaxf(p0, p1), fmaxf(p2, p3));
        vv = m + e;                           // v_new[jj] — next step's input
    }

    // ---- epilogue: + transitions[:, STOP], then block argmax (first-index wins)
    float vf = vv + tr[jj * NL + STOP_LBL];
    if (lane < 32) vfin[jj] = vf;
    __syncthreads();

    if (tid < 64) {
        float v0 = vfin[tid];
        float v1 = vfin[tid + 64];
        float val; int idx;
        if (v1 > v0) { val = v1; idx = tid + 64; } else { val = v0; idx = tid; }
#pragma unroll
        for (int off = 32; off >= 1; off >>= 1) {
            float ov = __shfl_xor(val, off, 64);
            int   oi = __shfl_xor(idx, off, 64);
            if (ov > val || (ov == val && oi < idx)) { val = ov; idx = oi; }
        }
        if (tid == 0) {
            out[b]      = val;           // best_final_score
            out[NB + b] = (float)idx;    // best_final_label (float-encoded)
        }
    }
}

extern "C" void kernel_launch(void* const* d_in, const int* in_sizes, int n_in,
                              void* d_out, int out_size, void* d_ws, size_t ws_size,
                              hipStream_t stream) {
    const float* em = (const float*)d_in[0];   // [128, 2048, 128] f32
    const float* tr = (const float*)d_in[1];   // [128, 128] f32
    float* out = (float*)d_out;                // [128] scores ++ [128] labels
    crf_viterbi<<<NB, 256, 0, stream>>>(em, tr, out);
}